// Round 2
// baseline (308.083 us; speedup 1.0000x reference)
//
#include <hip/hip_runtime.h>
#include <math.h>

#define TOK 4096
#define DM  512
#define HF  2048
#define NE  8

typedef __bf16 bf16x8 __attribute__((ext_vector_type(8)));
typedef float  floatx4 __attribute__((ext_vector_type(4)));

// float -> bf16 (round-to-nearest-even), raw ushort bits
__device__ __forceinline__ unsigned short f2b(float f) {
    union { float f; unsigned u; } v; v.f = f;
    return (unsigned short)((v.u + 0x7fffu + ((v.u >> 16) & 1u)) >> 16);
}

// async global->LDS, 16 bytes per lane (dest = wave-uniform base + lane*16)
__device__ __forceinline__ void load_lds16(const void* g, void* l) {
    __builtin_amdgcn_global_load_lds(
        (__attribute__((address_space(1))) unsigned int*)g,
        (__attribute__((address_space(3))) unsigned int*)l, 16, 0, 0);
}

__global__ void k_zero(int* p) {
    if (threadIdx.x < 32) p[threadIdx.x] = 0;
}

// zero the fp32 output (needed for split-K atomic accumulate)
__global__ __launch_bounds__(256)
void k_zero_out(float4* p) {
    p[blockIdx.x * 256 + threadIdx.x] = make_float4(0.f, 0.f, 0.f, 0.f);
}

// one wave per token: logits = x[t] @ Wr + br ; routes[t] = argmax
__global__ __launch_bounds__(64)
void k_router(const float* __restrict__ x, const float* __restrict__ Wr,
              const float* __restrict__ br, int* __restrict__ routes,
              int* __restrict__ counts) {
    int t = blockIdx.x;
    int lane = threadIdx.x;
    float acc[NE];
#pragma unroll
    for (int e = 0; e < NE; e++) acc[e] = 0.f;
    const float* xr = x + (size_t)t * DM;
    for (int d = lane; d < DM; d += 64) {
        float xv = xr[d];
        const float* w = Wr + (size_t)d * NE;
#pragma unroll
        for (int e = 0; e < NE; e++) acc[e] += xv * w[e];
    }
#pragma unroll
    for (int off = 32; off > 0; off >>= 1) {
#pragma unroll
        for (int e = 0; e < NE; e++) acc[e] += __shfl_down(acc[e], off, 64);
    }
    if (lane == 0) {
        int best = 0; float bv = acc[0] + br[0];
#pragma unroll
        for (int e = 1; e < NE; e++) {
            float v = acc[e] + br[e];
            if (v > bv) { bv = v; best = e; }   // strict > == first-max (jnp.argmax)
        }
        routes[t] = best;
        atomicAdd(&counts[best], 1);
    }
}

__global__ void k_scan(const int* __restrict__ counts, int* __restrict__ offsets) {
    if (threadIdx.x == 0 && blockIdx.x == 0) {
        int s = 0;
        for (int e = 0; e < NE; e++) { offsets[e] = s; s += counts[e]; }
        offsets[NE] = s;
    }
}

__global__ void k_scatter(const int* __restrict__ routes, const int* __restrict__ offsets,
                          int* __restrict__ cursor, int* __restrict__ perm) {
    int t = blockIdx.x * blockDim.x + threadIdx.x;
    if (t >= TOK) return;
    int e = routes[t];
    int p = atomicAdd(&cursor[e], 1);
    perm[offsets[e] + p] = t;
}

// gather x rows into expert-grouped bf16 matrix xg[g][d]
__global__ __launch_bounds__(64)
void k_gather(const float* __restrict__ x, const int* __restrict__ perm,
              unsigned short* __restrict__ xg) {
    int g = blockIdx.x;
    int lane = threadIdx.x;
    int t = perm[g];
    const float4* src = (const float4*)(x + (size_t)t * DM);
    unsigned short* dst = xg + (size_t)g * DM;
#pragma unroll
    for (int i = 0; i < 2; i++) {
        int idx = lane + i * 64;
        float4 v = src[idx];
        ushort4 o; o.x = f2b(v.x); o.y = f2b(v.y); o.z = f2b(v.z); o.w = f2b(v.w);
        *(ushort4*)(dst + idx * 4) = o;
    }
}

// in: [E][K][N] fp32  ->  out: [E][N][K] bf16   (64x64 LDS-tiled transpose)
__global__ __launch_bounds__(256)
void k_transpose(const float* __restrict__ in, unsigned short* __restrict__ out,
                 int K, int N) {
    int e  = blockIdx.z;
    int n0 = blockIdx.x * 64;
    int k0 = blockIdx.y * 64;
    __shared__ unsigned short tile[64][68];
    int tid = threadIdx.x;
    int tr = tid >> 4;   // 0..15
    int tc = tid & 15;   // 0..15
    const float* src = in + (size_t)e * K * N;
#pragma unroll
    for (int rr = 0; rr < 4; rr++) {
        int r = tr * 4 + rr;
        const float4 v = *(const float4*)(src + (size_t)(k0 + r) * N + n0 + tc * 4);
        tile[r][tc * 4 + 0] = f2b(v.x);
        tile[r][tc * 4 + 1] = f2b(v.y);
        tile[r][tc * 4 + 2] = f2b(v.z);
        tile[r][tc * 4 + 3] = f2b(v.w);
    }
    __syncthreads();
    unsigned short* dst = out + (size_t)e * N * K;
#pragma unroll
    for (int rr = 0; rr < 4; rr++) {
        int nrow = tr * 4 + rr;
        ushort4 o;
        o.x = tile[tc * 4 + 0][nrow];
        o.y = tile[tc * 4 + 1][nrow];
        o.z = tile[tc * 4 + 2][nrow];
        o.w = tile[tc * 4 + 3][nrow];
        *(ushort4*)(dst + (size_t)(n0 + nrow) * K + k0 + tc * 4) = o;
    }
}

// Grouped GEMM: C[M,N] = A[M,K] (grouped rows, bf16) x Bt[N,K]^T (bf16)
// Tile: TM x 128, 4 waves (2x2), each (TM/2) x 64.
// FC1 (KSPLIT=1): epilogue = GELU(acc + b1) -> hg (bf16).
// FC2 (KSPLIT>1): each z-slice handles KD/KSPLIT of K; atomicAdd fp32 into
//                 zero-initialized out, bias added by slice ks==0 only.
template <int KD, int ND, int TM, bool FC1, int KSPLIT>
__global__ __launch_bounds__(256)
void k_gemm(const unsigned short* __restrict__ A,
            const unsigned short* __restrict__ Bt,
            const float* __restrict__ bias,
            unsigned short* __restrict__ hg,
            float* __restrict__ out,
            const int* __restrict__ offsets,
            const int* __restrict__ perm) {
    const int e  = blockIdx.z / KSPLIT;
    const int ks = blockIdx.z % KSPLIT;
    const int seg0 = offsets[e];
    const int cnt  = offsets[e + 1] - seg0;
    const int m0 = blockIdx.y * TM;
    if (m0 >= cnt) return;
    const int n0 = blockIdx.x * 128;

    constexpr int MI = TM / 32;   // 16-row A fragments per wave
    __shared__ unsigned short As[TM * 32];
    __shared__ unsigned short Bs[128 * 32];

    const unsigned short* Aexp = A + (size_t)seg0 * KD;
    const unsigned short* Bexp = Bt + (size_t)e * ND * KD;

    const int tid  = threadIdx.x;
    const int lane = tid & 63;
    const int wave = tid >> 6;
    const int wm = (wave >> 1) * (TM / 2);
    const int wn = (wave & 1) * 64;
    const int aRow = wm + (lane & 15);
    const int bRow = wn + (lane & 15);
    const int kOff = (lane >> 4) * 8;

    floatx4 acc[MI][4];
#pragma unroll
    for (int i = 0; i < MI; i++)
#pragma unroll
        for (int j = 0; j < 4; j++)
#pragma unroll
            for (int r = 0; r < 4; r++) acc[i][j][r] = 0.f;

    const int kBase = ks * (KD / KSPLIT);
    const int kEnd  = kBase + (KD / KSPLIT);
    for (int k0 = kBase; k0 < kEnd; k0 += 32) {
#pragma unroll
        for (int r = 0; r < TM / 64; r++) {
            int fo  = tid * 16 + r * 4096;   // byte offset into A LDS tile
            int row = fo >> 6;               // 64B (32 bf16) per row
            int kb  = (fo & 63) >> 1;
            load_lds16(Aexp + (size_t)(m0 + row) * KD + k0 + kb, (char*)As + fo);
        }
#pragma unroll
        for (int r = 0; r < 2; r++) {
            int fo  = tid * 16 + r * 4096;
            int row = fo >> 6;
            int kb  = (fo & 63) >> 1;
            load_lds16(Bexp + (size_t)(n0 + row) * KD + k0 + kb, (char*)Bs + fo);
        }
        __syncthreads();
        bf16x8 af[MI], bfr[4];
#pragma unroll
        for (int t = 0; t < MI; t++) af[t]  = *(const bf16x8*)&As[(aRow + t * 16) * 32 + kOff];
#pragma unroll
        for (int t = 0; t < 4; t++)  bfr[t] = *(const bf16x8*)&Bs[(bRow + t * 16) * 32 + kOff];
#pragma unroll
        for (int i = 0; i < MI; i++)
#pragma unroll
            for (int j = 0; j < 4; j++)
                acc[i][j] = __builtin_amdgcn_mfma_f32_16x16x32_bf16(af[i], bfr[j], acc[i][j], 0, 0, 0);
        __syncthreads();
    }

    // epilogue: C/D layout col=lane&15, row=(lane>>4)*4+reg
    const int rq = (lane >> 4) * 4;
    const int cl = lane & 15;
#pragma unroll
    for (int j = 0; j < 4; j++) {
        int col = n0 + wn + j * 16 + cl;
        float bv = (!FC1 && ks != 0) ? 0.f : bias[(size_t)e * ND + col];
#pragma unroll
        for (int i = 0; i < MI; i++) {
#pragma unroll
            for (int r = 0; r < 4; r++) {
                int grow = m0 + wm + i * 16 + rq + r;
                if (grow < cnt) {
                    float v = acc[i][j][r] + bv;
                    if constexpr (FC1) {
                        v = 0.5f * v * (1.0f + erff(v * 0.70710678118654752f)); // exact GELU
                        hg[(size_t)(seg0 + grow) * ND + col] = f2b(v);
                    } else {
                        int tok = perm[seg0 + grow];
                        if constexpr (KSPLIT == 1)
                            out[(size_t)tok * ND + col] = v;
                        else
                            atomicAdd(&out[(size_t)tok * ND + col], v);
                    }
                }
            }
        }
    }
}

extern "C" void kernel_launch(void* const* d_in, const int* in_sizes, int n_in,
                              void* d_out, int out_size, void* d_ws, size_t ws_size,
                              hipStream_t stream) {
    const float* x  = (const float*)d_in[0];
    const float* Wr = (const float*)d_in[1];
    const float* br = (const float*)d_in[2];
    const float* W1 = (const float*)d_in[3];
    const float* b1 = (const float*)d_in[4];
    const float* W2 = (const float*)d_in[5];
    const float* b2 = (const float*)d_in[6];
    float* out = (float*)d_out;

    char* ws = (char*)d_ws;
    int* routes  = (int*)ws;            // [4096]
    int* perm    = routes + TOK;        // [4096]
    int* counts  = perm + TOK;          // [8]
    int* cursor  = counts + 8;          // [8]
    int* offsets = cursor + 8;          // [9]
    unsigned short* xg  = (unsigned short*)(ws + 65536);     // [4096][512]  bf16  (4 MB)
    unsigned short* hg  = xg + (size_t)TOK * DM;             // [4096][2048] bf16  (16 MB)
    unsigned short* W1t = hg + (size_t)TOK * HF;             // [E][H][D]    bf16  (16.8 MB)
    unsigned short* W2t = W1t + (size_t)NE * HF * DM;        // [E][D][H]    bf16  (16.8 MB)
    // A-tile overruns past the grouped matrices land in the next allocated
    // buffer (valid memory, non-NaN bf16 bit patterns); rows >= cnt never stored.

    k_zero_out<<<TOK * DM / 1024, 256, 0, stream>>>((float4*)out);
    k_zero<<<1, 64, 0, stream>>>(counts);
    k_router<<<TOK, 64, 0, stream>>>(x, Wr, br, routes, counts);
    k_scan<<<1, 1, 0, stream>>>(counts, offsets);
    k_scatter<<<16, 256, 0, stream>>>(routes, offsets, cursor, perm);
    k_gather<<<TOK, 64, 0, stream>>>(x, perm, xg);
    k_transpose<<<dim3(HF / 64, DM / 64, NE), 256, 0, stream>>>(W1, W1t, DM, HF);
    k_transpose<<<dim3(DM / 64, HF / 64, NE), 256, 0, stream>>>(W2, W2t, HF, DM);
    // fc1: TM=64 tiles -> ~1100 active blocks; GELU fused, no split-K.
    k_gemm<DM, HF, 64, true, 1><<<dim3(HF / 128, TOK / 64, NE), 256, 0, stream>>>(
        xg, W1t, b1, hg, nullptr, offsets, nullptr);
    // fc2: split-K=4 -> ~576 active blocks; atomic accumulate into zeroed out.
    k_gemm<HF, DM, 128, false, 4><<<dim3(DM / 128, TOK / 128, NE * 4), 256, 0, stream>>>(
        hg, W2t, b2, nullptr, out, offsets, perm);
}

// Round 3
// 271.156 us; speedup vs baseline: 1.1362x; 1.1362x over previous
//
#include <hip/hip_runtime.h>
#include <math.h>

#define TOK 4096
#define DM  512
#define HF  2048
#define NE  8

typedef __bf16 bf16x8 __attribute__((ext_vector_type(8)));
typedef float  floatx4 __attribute__((ext_vector_type(4)));

// float -> bf16 (round-to-nearest-even), raw ushort bits
__device__ __forceinline__ unsigned short f2b(float f) {
    union { float f; unsigned u; } v; v.f = f;
    return (unsigned short)((v.u + 0x7fffu + ((v.u >> 16) & 1u)) >> 16);
}

// async global->LDS, 16 bytes per lane (dest = wave-uniform base + lane*16)
__device__ __forceinline__ void load_lds16(const void* g, void* l) {
    __builtin_amdgcn_global_load_lds(
        (__attribute__((address_space(1))) unsigned int*)g,
        (__attribute__((address_space(3))) unsigned int*)l, 16, 0, 0);
}

__global__ void k_zero(int* p) {
    if (threadIdx.x < 32) p[threadIdx.x] = 0;
}

// one wave per token: logits = x[t] @ Wr + br ; routes[t] = argmax
__global__ __launch_bounds__(64)
void k_router(const float* __restrict__ x, const float* __restrict__ Wr,
              const float* __restrict__ br, int* __restrict__ routes,
              int* __restrict__ counts) {
    int t = blockIdx.x;
    int lane = threadIdx.x;
    float acc[NE];
#pragma unroll
    for (int e = 0; e < NE; e++) acc[e] = 0.f;
    const float* xr = x + (size_t)t * DM;
    for (int d = lane; d < DM; d += 64) {
        float xv = xr[d];
        const float* w = Wr + (size_t)d * NE;
#pragma unroll
        for (int e = 0; e < NE; e++) acc[e] += xv * w[e];
    }
#pragma unroll
    for (int off = 32; off > 0; off >>= 1) {
#pragma unroll
        for (int e = 0; e < NE; e++) acc[e] += __shfl_down(acc[e], off, 64);
    }
    if (lane == 0) {
        int best = 0; float bv = acc[0] + br[0];
#pragma unroll
        for (int e = 1; e < NE; e++) {
            float v = acc[e] + br[e];
            if (v > bv) { bv = v; best = e; }   // strict > == first-max (jnp.argmax)
        }
        routes[t] = best;
        atomicAdd(&counts[best], 1);
    }
}

__global__ void k_scan(const int* __restrict__ counts, int* __restrict__ offsets) {
    if (threadIdx.x == 0 && blockIdx.x == 0) {
        int s = 0;
        for (int e = 0; e < NE; e++) { offsets[e] = s; s += counts[e]; }
        offsets[NE] = s;
    }
}

__global__ void k_scatter(const int* __restrict__ routes, const int* __restrict__ offsets,
                          int* __restrict__ cursor, int* __restrict__ perm) {
    int t = blockIdx.x * blockDim.x + threadIdx.x;
    if (t >= TOK) return;
    int e = routes[t];
    int p = atomicAdd(&cursor[e], 1);
    perm[offsets[e] + p] = t;
}

// gather x rows into expert-grouped bf16 matrix xg[g][d]
__global__ __launch_bounds__(64)
void k_gather(const float* __restrict__ x, const int* __restrict__ perm,
              unsigned short* __restrict__ xg) {
    int g = blockIdx.x;
    int lane = threadIdx.x;
    int t = perm[g];
    const float4* src = (const float4*)(x + (size_t)t * DM);
    unsigned short* dst = xg + (size_t)g * DM;
#pragma unroll
    for (int i = 0; i < 2; i++) {
        int idx = lane + i * 64;
        float4 v = src[idx];
        ushort4 o; o.x = f2b(v.x); o.y = f2b(v.y); o.z = f2b(v.z); o.w = f2b(v.w);
        *(ushort4*)(dst + idx * 4) = o;
    }
}

// in: [E][K][N] fp32  ->  out: [E][N][K] bf16   (64x64 LDS-tiled transpose)
__global__ __launch_bounds__(256)
void k_transpose(const float* __restrict__ in, unsigned short* __restrict__ out,
                 int K, int N) {
    int e  = blockIdx.z;
    int n0 = blockIdx.x * 64;
    int k0 = blockIdx.y * 64;
    __shared__ unsigned short tile[64][68];
    int tid = threadIdx.x;
    int tr = tid >> 4;   // 0..15
    int tc = tid & 15;   // 0..15
    const float* src = in + (size_t)e * K * N;
#pragma unroll
    for (int rr = 0; rr < 4; rr++) {
        int r = tr * 4 + rr;
        const float4 v = *(const float4*)(src + (size_t)(k0 + r) * N + n0 + tc * 4);
        tile[r][tc * 4 + 0] = f2b(v.x);
        tile[r][tc * 4 + 1] = f2b(v.y);
        tile[r][tc * 4 + 2] = f2b(v.z);
        tile[r][tc * 4 + 3] = f2b(v.w);
    }
    __syncthreads();
    unsigned short* dst = out + (size_t)e * N * K;
#pragma unroll
    for (int rr = 0; rr < 4; rr++) {
        int nrow = tr * 4 + rr;
        ushort4 o;
        o.x = tile[tc * 4 + 0][nrow];
        o.y = tile[tc * 4 + 1][nrow];
        o.z = tile[tc * 4 + 2][nrow];
        o.w = tile[tc * 4 + 3][nrow];
        *(ushort4*)(dst + (size_t)(n0 + nrow) * K + k0 + tc * 4) = o;
    }
}

// Grouped GEMM: C[M,N] = A[M,K] (grouped rows, bf16) x Bt[N,K]^T (bf16)
// Tile: TM x 128, 4 waves (2x2), each (TM/2) x 64. Double-buffered LDS:
// one __syncthreads per K-iter; prefetch of tile k+1 overlaps MFMA of tile k.
// FC1 (KSPLIT=1): epilogue = GELU(acc + b1) -> hg (bf16).
// FC2 (KSPLIT=2): z-slice ks handles KD/KSPLIT of K; partials -> pbuf[ks] (no atomics).
template <int KD, int ND, int TM, bool FC1, int KSPLIT>
__global__ __launch_bounds__(256)
void k_gemm(const unsigned short* __restrict__ A,
            const unsigned short* __restrict__ Bt,
            const float* __restrict__ bias,
            unsigned short* __restrict__ hg,
            float* __restrict__ pbuf,
            const int* __restrict__ offsets) {
    const int e  = blockIdx.z / KSPLIT;
    const int ks = blockIdx.z % KSPLIT;
    const int seg0 = offsets[e];
    const int cnt  = offsets[e + 1] - seg0;
    const int m0 = blockIdx.y * TM;
    if (m0 >= cnt) return;
    const int n0 = blockIdx.x * 128;

    constexpr int MI = TM / 32;   // 16-row A fragments per wave
    __shared__ unsigned short As[2][TM * 32];
    __shared__ unsigned short Bs[2][128 * 32];

    const unsigned short* Aexp = A + (size_t)seg0 * KD;
    const unsigned short* Bexp = Bt + (size_t)e * ND * KD;

    const int tid  = threadIdx.x;
    const int lane = tid & 63;
    const int wave = tid >> 6;
    const int wm = (wave >> 1) * (TM / 2);
    const int wn = (wave & 1) * 64;
    const int aRow = wm + (lane & 15);
    const int bRow = wn + (lane & 15);
    const int kOff = (lane >> 4) * 8;

    auto stage = [&](int k0, int buf) {
#pragma unroll
        for (int r = 0; r < TM / 64; r++) {
            int fo  = tid * 16 + r * 4096;   // byte offset into A LDS tile
            int row = fo >> 6;               // 64B (32 bf16) per row
            int kb  = (fo & 63) >> 1;
            load_lds16(Aexp + (size_t)(m0 + row) * KD + k0 + kb, (char*)As[buf] + fo);
        }
#pragma unroll
        for (int r = 0; r < 2; r++) {
            int fo  = tid * 16 + r * 4096;
            int row = fo >> 6;
            int kb  = (fo & 63) >> 1;
            load_lds16(Bexp + (size_t)(n0 + row) * KD + k0 + kb, (char*)Bs[buf] + fo);
        }
    };

    floatx4 acc[MI][4];
#pragma unroll
    for (int i = 0; i < MI; i++)
#pragma unroll
        for (int j = 0; j < 4; j++)
#pragma unroll
            for (int r = 0; r < 4; r++) acc[i][j][r] = 0.f;

    const int kBase = ks * (KD / KSPLIT);
    const int kEnd  = kBase + (KD / KSPLIT);
    stage(kBase, 0);
    int cur = 0;
    for (int k0 = kBase; k0 < kEnd; k0 += 32) {
        __syncthreads();   // drains vmcnt: buf `cur` staged, prior reads of cur^1 done
        if (k0 + 32 < kEnd) stage(k0 + 32, cur ^ 1);   // async prefetch, overlaps MFMA
        bf16x8 af[MI], bfr[4];
#pragma unroll
        for (int t = 0; t < MI; t++) af[t]  = *(const bf16x8*)&As[cur][(aRow + t * 16) * 32 + kOff];
#pragma unroll
        for (int t = 0; t < 4; t++)  bfr[t] = *(const bf16x8*)&Bs[cur][(bRow + t * 16) * 32 + kOff];
#pragma unroll
        for (int i = 0; i < MI; i++)
#pragma unroll
            for (int j = 0; j < 4; j++)
                acc[i][j] = __builtin_amdgcn_mfma_f32_16x16x32_bf16(af[i], bfr[j], acc[i][j], 0, 0, 0);
        cur ^= 1;
    }

    // epilogue: C/D layout col=lane&15, row=(lane>>4)*4+reg
    const int rq = (lane >> 4) * 4;
    const int cl = lane & 15;
#pragma unroll
    for (int j = 0; j < 4; j++) {
        int col = n0 + wn + j * 16 + cl;
        float bv = FC1 ? bias[(size_t)e * ND + col] : 0.f;
#pragma unroll
        for (int i = 0; i < MI; i++) {
#pragma unroll
            for (int r = 0; r < 4; r++) {
                int grow = m0 + wm + i * 16 + rq + r;
                if (grow < cnt) {
                    float v = acc[i][j][r] + bv;
                    if constexpr (FC1) {
                        v = 0.5f * v * (1.0f + erff(v * 0.70710678118654752f)); // exact GELU
                        hg[(size_t)(seg0 + grow) * ND + col] = f2b(v);
                    } else {
                        pbuf[((size_t)ks * TOK + seg0 + grow) * ND + col] = v;
                    }
                }
            }
        }
    }
}

// out[perm[g]][:] = pbuf[0][g][:] + pbuf[1][g][:] + b2[e(g)][:]
// Writes EVERY output element (total == TOK since drop_tokens=False).
__global__ __launch_bounds__(128)
void k_reduce(const float* __restrict__ pbuf, const int* __restrict__ perm,
              const int* __restrict__ offsets, const float* __restrict__ b2,
              float* __restrict__ out) {
    int g = blockIdx.x;
    int tok = perm[g];
    int e = 0;
#pragma unroll
    for (int i = 1; i < NE; i++) e += (g >= offsets[i]);
    int c = threadIdx.x * 4;
    float4 a  = *(const float4*)&pbuf[(size_t)g * DM + c];
    float4 b  = *(const float4*)&pbuf[((size_t)TOK + g) * DM + c];
    float4 bb = *(const float4*)&b2[(size_t)e * DM + c];
    float4 o;
    o.x = a.x + b.x + bb.x; o.y = a.y + b.y + bb.y;
    o.z = a.z + b.z + bb.z; o.w = a.w + b.w + bb.w;
    *(float4*)&out[(size_t)tok * DM + c] = o;
}

extern "C" void kernel_launch(void* const* d_in, const int* in_sizes, int n_in,
                              void* d_out, int out_size, void* d_ws, size_t ws_size,
                              hipStream_t stream) {
    const float* x  = (const float*)d_in[0];
    const float* Wr = (const float*)d_in[1];
    const float* br = (const float*)d_in[2];
    const float* W1 = (const float*)d_in[3];
    const float* b1 = (const float*)d_in[4];
    const float* W2 = (const float*)d_in[5];
    const float* b2 = (const float*)d_in[6];
    float* out = (float*)d_out;

    char* ws = (char*)d_ws;
    int* routes  = (int*)ws;            // [4096]
    int* perm    = routes + TOK;        // [4096]
    int* counts  = perm + TOK;          // [8]
    int* cursor  = counts + 8;          // [8]
    int* offsets = cursor + 8;          // [9]
    unsigned short* xg  = (unsigned short*)(ws + 65536);     // [4096][512]  bf16  (4 MB)
    unsigned short* hg  = xg + (size_t)TOK * DM;             // [4096][2048] bf16  (16 MB)
    unsigned short* W1t = hg + (size_t)TOK * HF;             // [E][H][D]    bf16  (16.8 MB)
    unsigned short* W2t = W1t + (size_t)NE * HF * DM;        // [E][D][H]    bf16  (16.8 MB)
    // pbuf (fc2 split-K partials, 2 x 8 MB fp32) ALIASES W1t: W1t is dead once
    // fc1 completes, and fc2 only reads hg/W2t. fc2's A-tile overruns past hg
    // land in pbuf (valid memory; rows >= cnt never stored).
    float* pbuf = (float*)W1t;

    k_zero<<<1, 64, 0, stream>>>(counts);
    k_router<<<TOK, 64, 0, stream>>>(x, Wr, br, routes, counts);
    k_scan<<<1, 1, 0, stream>>>(counts, offsets);
    k_scatter<<<16, 256, 0, stream>>>(routes, offsets, cursor, perm);
    k_gather<<<TOK, 64, 0, stream>>>(x, perm, xg);
    k_transpose<<<dim3(HF / 64, DM / 64, NE), 256, 0, stream>>>(W1, W1t, DM, HF);
    k_transpose<<<dim3(DM / 64, HF / 64, NE), 256, 0, stream>>>(W2, W2t, HF, DM);
    // fc1: TM=64 -> ~1050 active blocks; GELU fused.
    k_gemm<DM, HF, 64, true, 1><<<dim3(HF / 128, TOK / 64, NE), 256, 0, stream>>>(
        xg, W1t, b1, hg, nullptr, offsets);
    // fc2: split-K=2 into separate partial buffers (no atomics), ~550 active blocks.
    k_gemm<HF, DM, 64, false, 2><<<dim3(DM / 128, TOK / 64, NE * 2), 256, 0, stream>>>(
        hg, W2t, nullptr, nullptr, pbuf, offsets);
    k_reduce<<<TOK, 128, 0, stream>>>(pbuf, perm, offsets, b2, out);
}

// Round 4
// 200.941 us; speedup vs baseline: 1.5332x; 1.3494x over previous
//
#include <hip/hip_runtime.h>
#include <math.h>

#define TOK 4096
#define DM  512
#define HF  2048
#define NE  8

typedef __bf16 bf16x8 __attribute__((ext_vector_type(8)));
typedef float  floatx4 __attribute__((ext_vector_type(4)));

// float -> bf16 (round-to-nearest-even), raw ushort bits
__device__ __forceinline__ unsigned short f2b(float f) {
    union { float f; unsigned u; } v; v.f = f;
    return (unsigned short)((v.u + 0x7fffu + ((v.u >> 16) & 1u)) >> 16);
}

// async global->LDS, 16 bytes per lane (dest = wave-uniform base + lane*16)
__device__ __forceinline__ void load_lds16(const void* g, void* l) {
    __builtin_amdgcn_global_load_lds(
        (__attribute__((address_space(1))) unsigned int*)g,
        (__attribute__((address_space(3))) unsigned int*)l, 16, 0, 0);
}

// one wave per token: logits = x[t] @ Wr + br ; routes[t] = argmax.
// NO atomics (round-3 lesson: 4096 device atomics on one cache line = 54 us).
__global__ __launch_bounds__(256)
void k_router(const float* __restrict__ x, const float* __restrict__ Wr,
              const float* __restrict__ br, int* __restrict__ routes) {
    int t = blockIdx.x * 4 + (threadIdx.x >> 6);
    int lane = threadIdx.x & 63;
    float acc[NE];
#pragma unroll
    for (int e = 0; e < NE; e++) acc[e] = 0.f;
    const float* xr = x + (size_t)t * DM;
#pragma unroll
    for (int d0 = 0; d0 < DM; d0 += 64) {
        float xv = xr[d0 + lane];
        const float* w = Wr + (size_t)(d0 + lane) * NE;
#pragma unroll
        for (int e = 0; e < NE; e++) acc[e] += xv * w[e];
    }
#pragma unroll
    for (int off = 32; off > 0; off >>= 1) {
#pragma unroll
        for (int e = 0; e < NE; e++) acc[e] += __shfl_down(acc[e], off, 64);
    }
    if (lane == 0) {
        int best = 0; float bv = acc[0] + br[0];
#pragma unroll
        for (int e = 1; e < NE; e++) {
            float v = acc[e] + br[e];
            if (v > bv) { bv = v; best = e; }   // strict > == first-max (jnp.argmax)
        }
        routes[t] = best;
    }
}

// Single block: histogram + prefix + perm placement, all contention in LDS.
// Replaces k_zero + k_scan + k_scatter (and the router's global atomics).
__global__ __launch_bounds__(1024)
void k_organize(const int* __restrict__ routes, int* __restrict__ offsets,
                int* __restrict__ perm) {
    __shared__ int cnt[NE], cur[NE], off[NE + 1];
    int tid = threadIdx.x;
    if (tid < NE) { cnt[tid] = 0; cur[tid] = 0; }
    __syncthreads();
    int t0 = tid * 4;
    int4 r = *(const int4*)&routes[t0];
    atomicAdd(&cnt[r.x], 1); atomicAdd(&cnt[r.y], 1);
    atomicAdd(&cnt[r.z], 1); atomicAdd(&cnt[r.w], 1);
    __syncthreads();
    if (tid == 0) {
        int s = 0;
#pragma unroll
        for (int e = 0; e < NE; e++) { off[e] = s; s += cnt[e]; }
        off[NE] = s;
    }
    __syncthreads();
    int p;
    p = atomicAdd(&cur[r.x], 1); perm[off[r.x] + p] = t0;
    p = atomicAdd(&cur[r.y], 1); perm[off[r.y] + p] = t0 + 1;
    p = atomicAdd(&cur[r.z], 1); perm[off[r.z] + p] = t0 + 2;
    p = atomicAdd(&cur[r.w], 1); perm[off[r.w] + p] = t0 + 3;
    if (tid < NE + 1) offsets[tid] = off[tid];
}

// gather x rows into expert-grouped bf16 matrix xg[g][d]
__global__ __launch_bounds__(64)
void k_gather(const float* __restrict__ x, const int* __restrict__ perm,
              unsigned short* __restrict__ xg) {
    int g = blockIdx.x;
    int lane = threadIdx.x;
    int t = perm[g];
    const float4* src = (const float4*)(x + (size_t)t * DM);
    unsigned short* dst = xg + (size_t)g * DM;
#pragma unroll
    for (int i = 0; i < 2; i++) {
        int idx = lane + i * 64;
        float4 v = src[idx];
        ushort4 o; o.x = f2b(v.x); o.y = f2b(v.y); o.z = f2b(v.z); o.w = f2b(v.w);
        *(ushort4*)(dst + idx * 4) = o;
    }
}

// in: [E][K][N] fp32  ->  out: [E][N][K] bf16   (64x64 LDS-tiled transpose)
__global__ __launch_bounds__(256)
void k_transpose(const float* __restrict__ in, unsigned short* __restrict__ out,
                 int K, int N) {
    int e  = blockIdx.z;
    int n0 = blockIdx.x * 64;
    int k0 = blockIdx.y * 64;
    __shared__ unsigned short tile[64][68];
    int tid = threadIdx.x;
    int tr = tid >> 4;   // 0..15
    int tc = tid & 15;   // 0..15
    const float* src = in + (size_t)e * K * N;
#pragma unroll
    for (int rr = 0; rr < 4; rr++) {
        int r = tr * 4 + rr;
        const float4 v = *(const float4*)(src + (size_t)(k0 + r) * N + n0 + tc * 4);
        tile[r][tc * 4 + 0] = f2b(v.x);
        tile[r][tc * 4 + 1] = f2b(v.y);
        tile[r][tc * 4 + 2] = f2b(v.z);
        tile[r][tc * 4 + 3] = f2b(v.w);
    }
    __syncthreads();
    unsigned short* dst = out + (size_t)e * N * K;
#pragma unroll
    for (int rr = 0; rr < 4; rr++) {
        int nrow = tr * 4 + rr;
        ushort4 o;
        o.x = tile[tc * 4 + 0][nrow];
        o.y = tile[tc * 4 + 1][nrow];
        o.z = tile[tc * 4 + 2][nrow];
        o.w = tile[tc * 4 + 3][nrow];
        *(ushort4*)(dst + (size_t)(n0 + nrow) * K + k0 + tc * 4) = o;
    }
}

// Grouped GEMM: C[M,N] = A[M,K] (grouped rows, bf16) x Bt[N,K]^T (bf16)
// Tile: TM x 128, 4 waves (2x2), each (TM/2) x 64. Double-buffered LDS:
// one __syncthreads per K-iter; prefetch of tile k+1 overlaps MFMA of tile k.
// FC1 (KSPLIT=1): epilogue = GELU(acc + b1) -> hg (bf16).
// FC2 (KSPLIT=2): z-slice ks handles KD/KSPLIT of K; partials -> pbuf[ks] (no atomics).
template <int KD, int ND, int TM, bool FC1, int KSPLIT>
__global__ __launch_bounds__(256)
void k_gemm(const unsigned short* __restrict__ A,
            const unsigned short* __restrict__ Bt,
            const float* __restrict__ bias,
            unsigned short* __restrict__ hg,
            float* __restrict__ pbuf,
            const int* __restrict__ offsets) {
    const int e  = blockIdx.z / KSPLIT;
    const int ks = blockIdx.z % KSPLIT;
    const int seg0 = offsets[e];
    const int cnt  = offsets[e + 1] - seg0;
    const int m0 = blockIdx.y * TM;
    if (m0 >= cnt) return;
    const int n0 = blockIdx.x * 128;

    constexpr int MI = TM / 32;   // 16-row A fragments per wave
    __shared__ unsigned short As[2][TM * 32];
    __shared__ unsigned short Bs[2][128 * 32];

    const unsigned short* Aexp = A + (size_t)seg0 * KD;
    const unsigned short* Bexp = Bt + (size_t)e * ND * KD;

    const int tid  = threadIdx.x;
    const int lane = tid & 63;
    const int wave = tid >> 6;
    const int wm = (wave >> 1) * (TM / 2);
    const int wn = (wave & 1) * 64;
    const int aRow = wm + (lane & 15);
    const int bRow = wn + (lane & 15);
    const int kOff = (lane >> 4) * 8;

    auto stage = [&](int k0, int buf) {
#pragma unroll
        for (int r = 0; r < TM / 64; r++) {
            int fo  = tid * 16 + r * 4096;   // byte offset into A LDS tile
            int row = fo >> 6;               // 64B (32 bf16) per row
            int kb  = (fo & 63) >> 1;
            load_lds16(Aexp + (size_t)(m0 + row) * KD + k0 + kb, (char*)As[buf] + fo);
        }
#pragma unroll
        for (int r = 0; r < 2; r++) {
            int fo  = tid * 16 + r * 4096;
            int row = fo >> 6;
            int kb  = (fo & 63) >> 1;
            load_lds16(Bexp + (size_t)(n0 + row) * KD + k0 + kb, (char*)Bs[buf] + fo);
        }
    };

    floatx4 acc[MI][4];
#pragma unroll
    for (int i = 0; i < MI; i++)
#pragma unroll
        for (int j = 0; j < 4; j++)
#pragma unroll
            for (int r = 0; r < 4; r++) acc[i][j][r] = 0.f;

    const int kBase = ks * (KD / KSPLIT);
    const int kEnd  = kBase + (KD / KSPLIT);
    stage(kBase, 0);
    int cur = 0;
    for (int k0 = kBase; k0 < kEnd; k0 += 32) {
        __syncthreads();   // drains vmcnt: buf `cur` staged, prior reads of cur^1 done
        if (k0 + 32 < kEnd) stage(k0 + 32, cur ^ 1);   // async prefetch, overlaps MFMA
        bf16x8 af[MI], bfr[4];
#pragma unroll
        for (int t = 0; t < MI; t++) af[t]  = *(const bf16x8*)&As[cur][(aRow + t * 16) * 32 + kOff];
#pragma unroll
        for (int t = 0; t < 4; t++)  bfr[t] = *(const bf16x8*)&Bs[cur][(bRow + t * 16) * 32 + kOff];
#pragma unroll
        for (int i = 0; i < MI; i++)
#pragma unroll
            for (int j = 0; j < 4; j++)
                acc[i][j] = __builtin_amdgcn_mfma_f32_16x16x32_bf16(af[i], bfr[j], acc[i][j], 0, 0, 0);
        cur ^= 1;
    }

    // epilogue: C/D layout col=lane&15, row=(lane>>4)*4+reg
    const int rq = (lane >> 4) * 4;
    const int cl = lane & 15;
#pragma unroll
    for (int j = 0; j < 4; j++) {
        int col = n0 + wn + j * 16 + cl;
        float bv = FC1 ? bias[(size_t)e * ND + col] : 0.f;
#pragma unroll
        for (int i = 0; i < MI; i++) {
#pragma unroll
            for (int r = 0; r < 4; r++) {
                int grow = m0 + wm + i * 16 + rq + r;
                if (grow < cnt) {
                    float v = acc[i][j][r] + bv;
                    if constexpr (FC1) {
                        v = 0.5f * v * (1.0f + erff(v * 0.70710678118654752f)); // exact GELU
                        hg[(size_t)(seg0 + grow) * ND + col] = f2b(v);
                    } else {
                        pbuf[((size_t)ks * TOK + seg0 + grow) * ND + col] = v;
                    }
                }
            }
        }
    }
}

// out[perm[g]][:] = pbuf[0][g][:] + pbuf[1][g][:] + b2[e(g)][:]
// Writes EVERY output element (total == TOK since drop_tokens=False).
__global__ __launch_bounds__(128)
void k_reduce(const float* __restrict__ pbuf, const int* __restrict__ perm,
              const int* __restrict__ offsets, const float* __restrict__ b2,
              float* __restrict__ out) {
    int g = blockIdx.x;
    int tok = perm[g];
    int e = 0;
#pragma unroll
    for (int i = 1; i < NE; i++) e += (g >= offsets[i]);
    int c = threadIdx.x * 4;
    float4 a  = *(const float4*)&pbuf[(size_t)g * DM + c];
    float4 b  = *(const float4*)&pbuf[((size_t)TOK + g) * DM + c];
    float4 bb = *(const float4*)&b2[(size_t)e * DM + c];
    float4 o;
    o.x = a.x + b.x + bb.x; o.y = a.y + b.y + bb.y;
    o.z = a.z + b.z + bb.z; o.w = a.w + b.w + bb.w;
    *(float4*)&out[(size_t)tok * DM + c] = o;
}

extern "C" void kernel_launch(void* const* d_in, const int* in_sizes, int n_in,
                              void* d_out, int out_size, void* d_ws, size_t ws_size,
                              hipStream_t stream) {
    const float* x  = (const float*)d_in[0];
    const float* Wr = (const float*)d_in[1];
    const float* br = (const float*)d_in[2];
    const float* W1 = (const float*)d_in[3];
    const float* b1 = (const float*)d_in[4];
    const float* W2 = (const float*)d_in[5];
    const float* b2 = (const float*)d_in[6];
    float* out = (float*)d_out;

    char* ws = (char*)d_ws;
    int* routes  = (int*)ws;            // [4096]
    int* perm    = routes + TOK;        // [4096]
    int* offsets = perm + TOK;          // [9]
    unsigned short* xg  = (unsigned short*)(ws + 65536);     // [4096][512]  bf16  (4 MB)
    unsigned short* hg  = xg + (size_t)TOK * DM;             // [4096][2048] bf16  (16 MB)
    unsigned short* W1t = hg + (size_t)TOK * HF;             // [E][H][D]    bf16  (16.8 MB)
    unsigned short* W2t = W1t + (size_t)NE * HF * DM;        // [E][D][H]    bf16  (16.8 MB)
    // pbuf (fc2 split-K partials, 2 x 8 MB fp32) ALIASES W1t: W1t is dead once
    // fc1 completes, and fc2 only reads hg/W2t. fc2's A-tile overruns past hg
    // land in pbuf (valid memory; rows >= cnt never stored).
    float* pbuf = (float*)W1t;

    k_router<<<TOK / 4, 256, 0, stream>>>(x, Wr, br, routes);
    k_organize<<<1, 1024, 0, stream>>>(routes, offsets, perm);
    k_gather<<<TOK, 64, 0, stream>>>(x, perm, xg);
    k_transpose<<<dim3(HF / 64, DM / 64, NE), 256, 0, stream>>>(W1, W1t, DM, HF);
    k_transpose<<<dim3(DM / 64, HF / 64, NE), 256, 0, stream>>>(W2, W2t, HF, DM);
    // fc1: TM=64 -> ~1050 active blocks; GELU fused.
    k_gemm<DM, HF, 64, true, 1><<<dim3(HF / 128, TOK / 64, NE), 256, 0, stream>>>(
        xg, W1t, b1, hg, nullptr, offsets);
    // fc2: split-K=2 into separate partial buffers (no atomics), ~550 active blocks.
    k_gemm<HF, DM, 64, false, 2><<<dim3(DM / 128, TOK / 64, NE * 2), 256, 0, stream>>>(
        hg, W2t, nullptr, nullptr, pbuf, offsets);
    k_reduce<<<TOK, 128, 0, stream>>>(pbuf, perm, offsets, b2, out);
}